// Round 8
// baseline (403.525 us; speedup 1.0000x reference)
//
#include <hip/hip_runtime.h>

// Fused: h = relu(X @ M + d), s0 = sum(h), where M = W^T @ RW (20x20),
// d = b @ RW + 1 -- precomputed by setup_kernel (algebraically identical to
// relu((X@W^T + b)@RW + 1)). Then n = #halvings of f32(s0) until <= 1;
// out = f32(s0) * 2^-n (exact power-of-2 scaling).
//
// Round-8: consolidation. R7's triple-dispatch experiment measured the
// invisible kernel: K_warm ~= 30 us (L3-delivery floor for 160 MB),
// K_cold ~= 65 us (30 + ~35 us of HBM writeback-drain contention from the
// harness's 800 MB restore/poison -- not addressable from kernel code).
// Remaining slack is launch count: finalize is merged into the fused kernel
// via the last-block ticket pattern (threadfence release -> atomicAdd ->
// last block threadfence-acquires and reduces). Setup zeroes the ticket.

#define D 20
#define BLOCK 256
#define RPT 2  // rows per thread

// d_ws layout:
//   [0, 32768)       : double partials[4096] (one per block)
//   [32768, +1600)   : float Mt[400], Mt[j*D+k] = M[k][j] (j-major)
//   [34368, +80)     : float dvec[20]
//   [34448, +4)      : int ticket counter (zeroed by setup_kernel)
#define WS_MT_OFF   32768
#define WS_DV_OFF   34368
#define WS_CTR_OFF  34448

__global__ void setup_kernel(const float* __restrict__ W,
                             const float* __restrict__ b,
                             const float* __restrict__ RW,
                             float* __restrict__ Mt,
                             float* __restrict__ dvec,
                             int* __restrict__ ticket) {
    const int tid = threadIdx.x;
    if (tid == 0) *ticket = 0;  // ws is poisoned 0xAA before every call
    for (int idx = tid; idx < D * D; idx += blockDim.x) {
        const int j = idx / D, k = idx % D;
        float s = 0.0f;
        for (int i = 0; i < D; ++i)
            s = fmaf(W[i * D + k], RW[i * D + j], s);
        Mt[idx] = s;  // idx == j*D + k
    }
    if (tid < D) {
        float s = 1.0f;
        for (int i = 0; i < D; ++i)
            s = fmaf(b[i], RW[i * D + tid], s);
        dvec[tid] = s;
    }
}

__global__ void __launch_bounds__(BLOCK)
fused_mlp_sum(const float* __restrict__ X,
              const float* __restrict__ Mt,
              const float* __restrict__ dvec,
              double* __restrict__ partials,
              int* __restrict__ ticket,
              float* __restrict__ out,
              int nrows) {
    __shared__ float wave_sums[BLOCK / 64];
    __shared__ int is_last;

    const int tid = threadIdx.x;
    const long long t = (long long)blockIdx.x * BLOCK + tid;
    const long long row0 = t * RPT;
    const bool valid = row0 < (long long)nrows;
    // Clamp instead of branch: uniform control flow lets the backend
    // scalarize the Mt/dvec loads (s_load -> SGPR, scalar pipe).
    const long long rbase = valid ? row0 : (long long)nrows - RPT;
    const float* xp = X + rbase * D;

    float x0[D], x1[D];
#pragma unroll
    for (int q = 0; q < 5; ++q) {
        float4 v = ((const float4*)xp)[q];
        x0[4 * q + 0] = v.x; x0[4 * q + 1] = v.y;
        x0[4 * q + 2] = v.z; x0[4 * q + 3] = v.w;
        float4 u = ((const float4*)(xp + D))[q];
        x1[4 * q + 0] = u.x; x1[4 * q + 1] = u.y;
        x1[4 * q + 2] = u.z; x1[4 * q + 3] = u.w;
    }

    float lsum = 0.0f;
#pragma unroll
    for (int j = 0; j < D; ++j) {
        float t0 = dvec[j];   // uniform addr + uniform CF -> s_load (SGPR)
        float t1 = t0;
#pragma unroll
        for (int k = 0; k < D; ++k) {
            const float m = Mt[j * D + k];  // uniform -> s_load, scalar pipe
            t0 = fmaf(x0[k], m, t0);        // v_fma with SGPR src
            t1 = fmaf(x1[k], m, t1);
        }
        lsum += fmaxf(t0, 0.0f) + fmaxf(t1, 0.0f);
    }
    lsum = valid ? lsum : 0.0f;  // mask clamped tail lanes

    // Wave (64-lane) shuffle reduction -> block LDS -> one plain store.
#pragma unroll
    for (int off = 32; off > 0; off >>= 1)
        lsum += __shfl_down(lsum, off, 64);
    if ((tid & 63) == 0) wave_sums[tid >> 6] = lsum;
    __syncthreads();
    if (tid == 0) {
        float bs = 0.0f;
#pragma unroll
        for (int w = 0; w < BLOCK / 64; ++w) bs += wave_sums[w];
        partials[blockIdx.x] = (double)bs;
        // Release: make the partial visible at agent scope (cross-XCD L2),
        // then take a ticket. Last block finalizes.
        __threadfence();
        const int old = atomicAdd(ticket, 1);
        is_last = (old == (int)gridDim.x - 1) ? 1 : 0;
    }
    __syncthreads();

    if (is_last) {
        __threadfence();  // acquire side: invalidate stale L2 lines
        __shared__ double wsum[BLOCK / 64];
        const int nparts = (int)gridDim.x;
        double s = 0.0;
        for (int i = tid; i < nparts; i += BLOCK) s += partials[i];
#pragma unroll
        for (int off = 32; off > 0; off >>= 1)
            s += __shfl_down(s, off, 64);
        if ((tid & 63) == 0) wsum[tid >> 6] = s;
        __syncthreads();
        if (tid == 0) {
            double s0 = 0.0;
#pragma unroll
            for (int w = 0; w < BLOCK / 64; ++w) s0 += wsum[w];
            float f = (float)s0;   // reference's s0 is f32
            int n = 0;
            while (f > 1.0f) { ++n; f *= 0.5f; }  // exact power-of-2 halvings
            out[0] = f;
        }
    }
}

extern "C" void kernel_launch(void* const* d_in, const int* in_sizes, int n_in,
                              void* d_out, int out_size, void* d_ws, size_t ws_size,
                              hipStream_t stream) {
    const float* X  = (const float*)d_in[0];
    const float* W  = (const float*)d_in[1];
    const float* b  = (const float*)d_in[2];
    const float* RW = (const float*)d_in[3];
    float* out = (float*)d_out;

    double* partials = (double*)d_ws;
    float*  Mt = (float*)((char*)d_ws + WS_MT_OFF);
    float*  dv = (float*)((char*)d_ws + WS_DV_OFF);
    int*    tk = (int*)((char*)d_ws + WS_CTR_OFF);

    const int nrows = in_sizes[0] / D;  // 2,000,000

    setup_kernel<<<1, 256, 0, stream>>>(W, b, RW, Mt, dv, tk);

    const long long nthreads = ((long long)nrows + RPT - 1) / RPT;  // 1,000,000
    const int blocks = (int)((nthreads + BLOCK - 1) / BLOCK);       // 3907
    fused_mlp_sum<<<blocks, BLOCK, 0, stream>>>(X, Mt, dv, partials, tk, out, nrows);
}

// Round 9
// 231.946 us; speedup vs baseline: 1.7397x; 1.7397x over previous
//
#include <hip/hip_runtime.h>

// ROUND 9 = revert to the round-5 kernel verbatim (best measured: 231.1 us).
// R8's merged last-block finalize collapsed codegen of the hot loop
// (VGPR 24: j/k loops rolled -> x arrays scratch-indexed -> 240 us latency-
// bound kernel). Keeping the finalize as a separate 1-block kernel keeps the
// hot kernel's full unroll + s_load scalarization intact.
//
// Fused math: h = relu(X @ M + d), s0 = sum(h), where M = W^T @ RW,
// d = b @ RW + 1 (precomputed by setup_kernel) -- algebraically identical to
// relu((X@W^T + b)@RW + 1). Then n = #halvings of f32(s0) until <= 1;
// out = f32(s0) * 2^-n (exact power-of-2 scaling).
//
// Measured ledger at this structure (R7 triple-dispatch experiment):
//   K_warm ~= 30 us (L3-resident X), K_cold ~= 60-65 us (~80 MB from HBM
//   concurrent with the harness's 800 MB writeback drain), harness restore/
//   poison traffic inside the timed window ~= 166 us, launches ~= 5 us.

#define D 20
#define BLOCK 256
#define RPT 2  // rows per thread

// d_ws layout:
//   [0, 32768)          : double partials[4096] (one per block)
//   [32768, +1600)      : float Mt[400], Mt[j*D+k] = M[k][j] (j-major)
//   [+1600, +1680)      : float dvec[20]
#define WS_PARTIALS_BYTES 32768

__global__ void setup_kernel(const float* __restrict__ W,
                             const float* __restrict__ b,
                             const float* __restrict__ RW,
                             float* __restrict__ Mt,
                             float* __restrict__ dvec) {
    const int tid = threadIdx.x;
    for (int idx = tid; idx < D * D; idx += blockDim.x) {
        const int j = idx / D, k = idx % D;
        float s = 0.0f;
        for (int i = 0; i < D; ++i)
            s = fmaf(W[i * D + k], RW[i * D + j], s);
        Mt[idx] = s;  // idx == j*D + k
    }
    if (tid < D) {
        float s = 1.0f;
        for (int i = 0; i < D; ++i)
            s = fmaf(b[i], RW[i * D + tid], s);
        dvec[tid] = s;
    }
}

__global__ void __launch_bounds__(BLOCK)
fused_mlp_sum(const float* __restrict__ X,
              const float* __restrict__ Mt,
              const float* __restrict__ dvec,
              double* __restrict__ partials,
              int nrows) {
    __shared__ float wave_sums[BLOCK / 64];

    const int tid = threadIdx.x;
    const long long t = (long long)blockIdx.x * BLOCK + tid;
    const long long row0 = t * RPT;
    const bool valid = row0 < (long long)nrows;
    // Clamp instead of branch: uniform control flow lets the backend
    // scalarize the Mt/dvec loads (s_load -> SGPR, scalar pipe).
    const long long rbase = valid ? row0 : (long long)nrows - RPT;
    const float* xp = X + rbase * D;

    float x0[D], x1[D];
#pragma unroll
    for (int q = 0; q < 5; ++q) {
        float4 v = ((const float4*)xp)[q];
        x0[4 * q + 0] = v.x; x0[4 * q + 1] = v.y;
        x0[4 * q + 2] = v.z; x0[4 * q + 3] = v.w;
        float4 u = ((const float4*)(xp + D))[q];
        x1[4 * q + 0] = u.x; x1[4 * q + 1] = u.y;
        x1[4 * q + 2] = u.z; x1[4 * q + 3] = u.w;
    }

    float lsum = 0.0f;
#pragma unroll
    for (int j = 0; j < D; ++j) {
        float t0 = dvec[j];   // uniform addr + uniform CF -> s_load (SGPR)
        float t1 = t0;
#pragma unroll
        for (int k = 0; k < D; ++k) {
            const float m = Mt[j * D + k];  // uniform -> s_load, scalar pipe
            t0 = fmaf(x0[k], m, t0);        // v_fma with SGPR src
            t1 = fmaf(x1[k], m, t1);
        }
        lsum += fmaxf(t0, 0.0f) + fmaxf(t1, 0.0f);
    }
    lsum = valid ? lsum : 0.0f;  // mask clamped tail lanes

    // Wave (64-lane) shuffle reduction -> block LDS -> one plain store.
#pragma unroll
    for (int off = 32; off > 0; off >>= 1)
        lsum += __shfl_down(lsum, off, 64);
    if ((tid & 63) == 0) wave_sums[tid >> 6] = lsum;
    __syncthreads();
    if (tid == 0) {
        float bs = 0.0f;
#pragma unroll
        for (int w = 0; w < BLOCK / 64; ++w) bs += wave_sums[w];
        partials[blockIdx.x] = (double)bs;  // no atomic: one slot per block
    }
}

__global__ void __launch_bounds__(1024)
finalize_kernel(const double* __restrict__ partials, int nparts,
                float* __restrict__ out) {
    __shared__ double wsum[16];
    const int tid = threadIdx.x;
    double s = 0.0;
    for (int i = tid; i < nparts; i += 1024) s += partials[i];
#pragma unroll
    for (int off = 32; off > 0; off >>= 1)
        s += __shfl_down(s, off, 64);
    if ((tid & 63) == 0) wsum[tid >> 6] = s;
    __syncthreads();
    if (tid == 0) {
        double s0 = 0.0;
#pragma unroll
        for (int w = 0; w < 16; ++w) s0 += wsum[w];
        float f = (float)s0;   // reference's s0 is f32
        int n = 0;
        while (f > 1.0f) { ++n; f *= 0.5f; }  // exact power-of-2 halvings
        out[0] = f;
    }
}

extern "C" void kernel_launch(void* const* d_in, const int* in_sizes, int n_in,
                              void* d_out, int out_size, void* d_ws, size_t ws_size,
                              hipStream_t stream) {
    const float* X  = (const float*)d_in[0];
    const float* W  = (const float*)d_in[1];
    const float* b  = (const float*)d_in[2];
    const float* RW = (const float*)d_in[3];
    float* out = (float*)d_out;

    double* partials = (double*)d_ws;
    float*  Mt = (float*)((char*)d_ws + WS_PARTIALS_BYTES);
    float*  dv = Mt + D * D;

    const int nrows = in_sizes[0] / D;  // 2,000,000

    setup_kernel<<<1, 256, 0, stream>>>(W, b, RW, Mt, dv);

    const long long nthreads = ((long long)nrows + RPT - 1) / RPT;  // 1,000,000
    const int blocks = (int)((nthreads + BLOCK - 1) / BLOCK);       // 3907
    fused_mlp_sum<<<blocks, BLOCK, 0, stream>>>(X, Mt, dv, partials, nrows);
    finalize_kernel<<<1, 1024, 0, stream>>>(partials, blocks, out);
}